// Round 1
// baseline (351.074 us; speedup 1.0000x reference)
//
#include <hip/hip_runtime.h>
#include <hip/hip_bf16.h>
#include <math.h>

typedef __bf16 bf16;
typedef __bf16 bf16x8 __attribute__((ext_vector_type(8)));
typedef float f32x4 __attribute__((ext_vector_type(4)));

#define DIM 768
#define HID 3072
#define HID2 1536
#define NLEV 9
#define SEQ 2048
#define ROWS 4096            // BATCH*SEQ
#define MAXPAD 5248          // ROWS + NLEV*128 (rounded)
#define MAXTILES 41          // MAXPAD/128

// ---------------- async global->LDS 16B ----------------
__device__ __forceinline__ void gld16(const void* g, void* l) {
    __builtin_amdgcn_global_load_lds(
        (const __attribute__((address_space(1))) void*)g,
        (__attribute__((address_space(3))) void*)l, 16, 0, 0);
}

// ---------------- LayerNorm -> bf16 ----------------
__global__ __launch_bounds__(256) void ln_kernel(const float* __restrict__ x,
                                                 const float* __restrict__ gamma,
                                                 const float* __restrict__ beta,
                                                 bf16* __restrict__ xn) {
    int row = blockIdx.x;
    int tid = threadIdx.x;
    const float* xr = x + (size_t)row * DIM;
    float v0 = xr[tid], v1 = xr[tid + 256], v2 = xr[tid + 512];
    float s = v0 + v1 + v2;
    float q = v0 * v0 + v1 * v1 + v2 * v2;
    for (int off = 32; off; off >>= 1) {
        s += __shfl_down(s, off, 64);
        q += __shfl_down(q, off, 64);
    }
    __shared__ float ss[4], qq[4];
    __shared__ float mean_s, rstd_s;
    int wv = tid >> 6, ln = tid & 63;
    if (ln == 0) { ss[wv] = s; qq[wv] = q; }
    __syncthreads();
    if (tid == 0) {
        float S = ss[0] + ss[1] + ss[2] + ss[3];
        float Q = qq[0] + qq[1] + qq[2] + qq[3];
        float m = S * (1.0f / DIM);
        float var = Q * (1.0f / DIM) - m * m;
        mean_s = m;
        rstd_s = rsqrtf(var + 1e-5f);
    }
    __syncthreads();
    float m = mean_s, r = rstd_s;
    bf16* xo = xn + (size_t)row * DIM;
    xo[tid]       = (bf16)((v0 - m) * r * gamma[tid]       + beta[tid]);
    xo[tid + 256] = (bf16)((v1 - m) * r * gamma[tid + 256] + beta[tid + 256]);
    xo[tid + 512] = (bf16)((v2 - m) * r * gamma[tid + 512] + beta[tid + 512]);
}

// ---------------- transpose fp32 [bz][R][C] -> bf16 [bz][C][R] ----------------
__global__ __launch_bounds__(256) void transpose_kernel(const float* __restrict__ in,
                                                        bf16* __restrict__ out,
                                                        int R, int C) {
    __shared__ float tile[32][33];
    int bx = blockIdx.x, by = blockIdx.y, bz = blockIdx.z;
    const float* inb = in + (size_t)bz * R * C;
    bf16* outb = out + (size_t)bz * R * C;
    int tx = threadIdx.x & 31, ty = threadIdx.x >> 5;  // ty 0..7
#pragma unroll
    for (int i = 0; i < 4; i++) {
        int r = by * 32 + ty + i * 8;
        tile[ty + i * 8][tx] = inb[(size_t)r * C + bx * 32 + tx];
    }
    __syncthreads();
#pragma unroll
    for (int i = 0; i < 4; i++) {
        int c = bx * 32 + ty + i * 8;
        outb[(size_t)c * R + by * 32 + tx] = (bf16)tile[tx][ty + i * 8];
    }
}

// ---------------- routing: histogram, softmax mix, sorted+padded row lists ----------------
__global__ __launch_bounds__(256) void routing_kernel(const int* __restrict__ levels_info,
                                                      const float* __restrict__ lmw,
                                                      float* __restrict__ mix,
                                                      int* __restrict__ row_index,
                                                      int* __restrict__ tile_meta,
                                                      float* __restrict__ zbuf) {
    __shared__ int cnt[NLEV], cur[NLEV], off[NLEV];
    __shared__ float mixv[NLEV];
    int tid = threadIdx.x;
    if (tid < NLEV) { cnt[tid] = 0; cur[tid] = 0; }
    __syncthreads();
    for (int s = tid; s < SEQ; s += 256) {
        int d = levels_info[s * 4];
        d = d < 0 ? 0 : (d > 8 ? 8 : d);
        atomicAdd(&cnt[d], 1);
    }
    for (int i = tid; i < MAXPAD; i += 256) row_index[i] = -1;
    if (tid < 16) zbuf[tid] = 0.0f;
    __syncthreads();
    if (tid == 0) {
        float mx = lmw[0];
        for (int l = 1; l < NLEV; l++) mx = fmaxf(mx, lmw[l]);
        float denom = 0.f;
        for (int l = 0; l < NLEV; l++) denom += (float)cnt[l] * expf(lmw[l] - mx);
        float inv = 1.0f / denom;
        int running = 0, t = 0;
        for (int l = 0; l < NLEV; l++) {
            mixv[l] = expf(lmw[l] - mx) * inv;
            off[l] = running;
            int seg = (2 * cnt[l] + 127) & ~127;
            for (int k = 0; k < seg / 128; k++) tile_meta[t++] = l;
            running += seg;
        }
        for (; t < MAXTILES; t++) tile_meta[t] = -1;
    }
    __syncthreads();
    for (int s = tid; s < SEQ; s += 256) {
        int d = levels_info[s * 4];
        d = d < 0 ? 0 : (d > 8 ? 8 : d);
        int p = atomicAdd(&cur[d], 2);
        row_index[off[d] + p]     = s;
        row_index[off[d] + p + 1] = s + SEQ;
        mix[s] = mixv[d];
    }
}

// ---------------- shared GEMM main loop: C[128,128] tile, BK=32 ----------------
// A tile staged as [128 rows][32 k] row-major, B^T tile identically ([n][k]).
__device__ __forceinline__ void gemm_loop(const bf16* ga0, const bf16* ga1,
                                          int stepa0, int stepa1,
                                          const bf16* gb0, const bf16* gb1, int stepb,
                                          bf16* As, bf16* Bs,
                                          f32x4 (&acc)[4][4], int ktiles) {
    int tid = threadIdx.x;
    int wv = tid >> 6;
    int lane = tid & 63;
    int wm = wv >> 1, wn = wv & 1;
    const bf16* arow = As + ((wm * 64) + (lane & 15)) * 32 + (lane >> 4) * 8;
    const bf16* brow = Bs + ((wn * 64) + (lane & 15)) * 32 + (lane >> 4) * 8;
    for (int kt = 0; kt < ktiles; ++kt) {
        gld16(ga0, As + wv * 512);
        gld16(ga1, As + 2048 + wv * 512);
        gld16(gb0, Bs + wv * 512);
        gld16(gb1, Bs + 2048 + wv * 512);
        ga0 += stepa0; ga1 += stepa1; gb0 += stepb; gb1 += stepb;
        __syncthreads();
        bf16x8 af[4], bfr[4];
#pragma unroll
        for (int i = 0; i < 4; i++) af[i] = *(const bf16x8*)(arow + i * 16 * 32);
#pragma unroll
        for (int j = 0; j < 4; j++) bfr[j] = *(const bf16x8*)(brow + j * 16 * 32);
#pragma unroll
        for (int i = 0; i < 4; i++)
#pragma unroll
            for (int j = 0; j < 4; j++)
                acc[i][j] = __builtin_amdgcn_mfma_f32_16x16x32_bf16(af[i], bfr[j], acc[i][j], 0, 0, 0);
        __syncthreads();
    }
}

#define ACC_INIT(acc) \
    _Pragma("unroll") for (int i = 0; i < 4; i++) \
    _Pragma("unroll") for (int j = 0; j < 4; j++) acc[i][j] = (f32x4){0.f, 0.f, 0.f, 0.f};

// ---------------- GEMM1: H = gelu(Xn @ W1 + b1) ----------------
__global__ __launch_bounds__(256) void gemm1_kernel(const bf16* __restrict__ Xn,
                                                    const bf16* __restrict__ W1t,
                                                    const float* __restrict__ b1,
                                                    bf16* __restrict__ H) {
    __shared__ __align__(16) bf16 As[4096], Bs[4096];
    int mb = blockIdx.x, nb = blockIdx.y, tid = threadIdx.x;
    int r0 = tid >> 2, cg = tid & 3;
    const bf16* ga0 = Xn + (size_t)(mb * 128 + r0) * DIM + cg * 8;
    const bf16* ga1 = ga0 + (size_t)64 * DIM;
    const bf16* gb0 = W1t + (size_t)(nb * 128 + r0) * DIM + cg * 8;
    const bf16* gb1 = gb0 + (size_t)64 * DIM;
    f32x4 acc[4][4];
    ACC_INIT(acc);
    gemm_loop(ga0, ga1, 32, 32, gb0, gb1, 32, As, Bs, acc, DIM / 32);
    int lane = tid & 63, wv = tid >> 6, wm = wv >> 1, wn = wv & 1;
    int rbase = mb * 128 + wm * 64 + ((lane >> 4) << 2);
    int cbase = nb * 128 + wn * 64 + (lane & 15);
#pragma unroll
    for (int j = 0; j < 4; j++) {
        int c = cbase + j * 16;
        float bias = b1[c];
#pragma unroll
        for (int i = 0; i < 4; i++)
#pragma unroll
            for (int r = 0; r < 4; r++) {
                int row = rbase + i * 16 + r;
                float v = acc[i][j][r] + bias;
                float g = 0.5f * v * (1.0f + erff(v * 0.70710678118f));
                H[(size_t)row * HID + c] = (bf16)g;
            }
    }
}

// ---------------- GEMM2: out = (1-mix) * (H @ W2 + b2) ----------------
__global__ __launch_bounds__(256) void gemm2_kernel(const bf16* __restrict__ H,
                                                    const bf16* __restrict__ W2t,
                                                    const float* __restrict__ b2,
                                                    const float* __restrict__ mix,
                                                    float* __restrict__ out) {
    __shared__ __align__(16) bf16 As[4096], Bs[4096];
    int mb = blockIdx.x, nb = blockIdx.y, tid = threadIdx.x;
    int r0 = tid >> 2, cg = tid & 3;
    const bf16* ga0 = H + (size_t)(mb * 128 + r0) * HID + cg * 8;
    const bf16* ga1 = ga0 + (size_t)64 * HID;
    const bf16* gb0 = W2t + (size_t)(nb * 128 + r0) * HID + cg * 8;
    const bf16* gb1 = gb0 + (size_t)64 * HID;
    f32x4 acc[4][4];
    ACC_INIT(acc);
    gemm_loop(ga0, ga1, 32, 32, gb0, gb1, 32, As, Bs, acc, HID / 32);
    int lane = tid & 63, wv = tid >> 6, wm = wv >> 1, wn = wv & 1;
    int rbase = mb * 128 + wm * 64 + ((lane >> 4) << 2);
    int cbase = nb * 128 + wn * 64 + (lane & 15);
#pragma unroll
    for (int j = 0; j < 4; j++) {
        int c = cbase + j * 16;
        float bias = b2[c];
#pragma unroll
        for (int i = 0; i < 4; i++)
#pragma unroll
            for (int r = 0; r < 4; r++) {
                int row = rbase + i * 16 + r;
                float mx = mix[row & (SEQ - 1)];
                out[(size_t)row * DIM + c] = (1.0f - mx) * (acc[i][j][r] + bias);
            }
    }
}

// ---------------- adapter GEMM1: HL = relu(gather(Xn) @ A1[lvl] + a1b[lvl]) ----------------
__global__ __launch_bounds__(256) void agemm1_kernel(const bf16* __restrict__ Xn,
                                                     const bf16* __restrict__ A1t,
                                                     const float* __restrict__ a1b,
                                                     const int* __restrict__ row_index,
                                                     const int* __restrict__ tile_meta,
                                                     const bf16* __restrict__ zbuf,
                                                     bf16* __restrict__ HL) {
    int t = blockIdx.x;
    int lvl = tile_meta[t];
    if (lvl < 0) return;
    __shared__ __align__(16) bf16 As[4096], Bs[4096];
    int nb = blockIdx.y, tid = threadIdx.x;
    int r0 = tid >> 2, cg = tid & 3;
    int ridx0 = row_index[t * 128 + r0];
    int ridx1 = row_index[t * 128 + 64 + r0];
    const bf16* ga0 = (ridx0 >= 0) ? (Xn + (size_t)ridx0 * DIM + cg * 8) : zbuf;
    const bf16* ga1 = (ridx1 >= 0) ? (Xn + (size_t)ridx1 * DIM + cg * 8) : zbuf;
    int sa0 = (ridx0 >= 0) ? 32 : 0;
    int sa1 = (ridx1 >= 0) ? 32 : 0;
    const bf16* Bl = A1t + (size_t)lvl * HID2 * DIM;
    const bf16* gb0 = Bl + (size_t)(nb * 128 + r0) * DIM + cg * 8;
    const bf16* gb1 = gb0 + (size_t)64 * DIM;
    f32x4 acc[4][4];
    ACC_INIT(acc);
    gemm_loop(ga0, ga1, sa0, sa1, gb0, gb1, 32, As, Bs, acc, DIM / 32);
    int lane = tid & 63, wv = tid >> 6, wm = wv >> 1, wn = wv & 1;
    int rbase = wm * 64 + ((lane >> 4) << 2);
    int cbase = nb * 128 + wn * 64 + (lane & 15);
#pragma unroll
    for (int j = 0; j < 4; j++) {
        int c = cbase + j * 16;
        float bias = a1b[lvl * HID2 + c];
#pragma unroll
        for (int i = 0; i < 4; i++)
#pragma unroll
            for (int r = 0; r < 4; r++) {
                int rl = rbase + i * 16 + r;
                float v = acc[i][j][r] + bias;
                HL[(size_t)(t * 128 + rl) * HID2 + c] = (bf16)fmaxf(v, 0.0f);
            }
    }
}

// ---------------- adapter GEMM2: out[gather rows] += mix * (HL @ A2[lvl] + a2b[lvl]) ----------------
__global__ __launch_bounds__(256) void agemm2_kernel(const bf16* __restrict__ HL,
                                                     const bf16* __restrict__ A2t,
                                                     const float* __restrict__ a2b,
                                                     const int* __restrict__ row_index,
                                                     const int* __restrict__ tile_meta,
                                                     const float* __restrict__ mix,
                                                     float* __restrict__ out) {
    int t = blockIdx.x;
    int lvl = tile_meta[t];
    if (lvl < 0) return;
    __shared__ __align__(16) bf16 As[4096], Bs[4096];
    int nb = blockIdx.y, tid = threadIdx.x;
    int r0 = tid >> 2, cg = tid & 3;
    const bf16* ga0 = HL + (size_t)(t * 128 + r0) * HID2 + cg * 8;
    const bf16* ga1 = ga0 + (size_t)64 * HID2;
    const bf16* Bl = A2t + (size_t)lvl * DIM * HID2;
    const bf16* gb0 = Bl + (size_t)(nb * 128 + r0) * HID2 + cg * 8;
    const bf16* gb1 = gb0 + (size_t)64 * HID2;
    f32x4 acc[4][4];
    ACC_INIT(acc);
    gemm_loop(ga0, ga1, 32, 32, gb0, gb1, 32, As, Bs, acc, HID2 / 32);
    int lane = tid & 63, wv = tid >> 6, wm = wv >> 1, wn = wv & 1;
    int rbase = wm * 64 + ((lane >> 4) << 2);
    int cbase = nb * 128 + wn * 64 + (lane & 15);
#pragma unroll
    for (int i = 0; i < 4; i++)
#pragma unroll
        for (int r = 0; r < 4; r++) {
            int rl = rbase + i * 16 + r;
            int rg = row_index[t * 128 + rl];
            if (rg >= 0) {
                float mx = mix[rg & (SEQ - 1)];
#pragma unroll
                for (int j = 0; j < 4; j++) {
                    int c = cbase + j * 16;
                    out[(size_t)rg * DIM + c] += mx * (acc[i][j][r] + a2b[lvl * DIM + c]);
                }
            }
        }
}

// ---------------- launch ----------------
extern "C" void kernel_launch(void* const* d_in, const int* in_sizes, int n_in,
                              void* d_out, int out_size, void* d_ws, size_t ws_size,
                              hipStream_t stream) {
    const float* x    = (const float*)d_in[0];
    const int* levels = (const int*)d_in[1];
    const float* gamma= (const float*)d_in[2];
    const float* beta = (const float*)d_in[3];
    const float* W1   = (const float*)d_in[4];
    const float* b1   = (const float*)d_in[5];
    const float* W2   = (const float*)d_in[6];
    const float* b2   = (const float*)d_in[7];
    const float* A1   = (const float*)d_in[8];
    const float* a1b  = (const float*)d_in[9];
    const float* A2   = (const float*)d_in[10];
    const float* a2b  = (const float*)d_in[11];
    const float* lmw  = (const float*)d_in[12];
    float* out = (float*)d_out;

    char* p = (char*)d_ws;
    auto alloc = [&](size_t bytes) {
        char* r = p;
        p += (bytes + 255) & ~(size_t)255;
        return r;
    };
    bf16* Xn   = (bf16*)alloc((size_t)ROWS * DIM * 2);
    bf16* W1t  = (bf16*)alloc((size_t)HID * DIM * 2);
    bf16* W2t  = (bf16*)alloc((size_t)DIM * HID * 2);
    bf16* A1t  = (bf16*)alloc((size_t)NLEV * HID2 * DIM * 2);
    bf16* A2t  = (bf16*)alloc((size_t)NLEV * DIM * HID2 * 2);
    bf16* H    = (bf16*)alloc((size_t)ROWS * HID * 2);
    bf16* HL   = (bf16*)alloc((size_t)MAXPAD * HID2 * 2);
    float* mix = (float*)alloc(SEQ * 4);
    int* row_index = (int*)alloc(MAXPAD * 4);
    int* tile_meta = (int*)alloc(MAXTILES * 4);
    float* zbuf    = (float*)alloc(64);

    ln_kernel<<<dim3(ROWS), dim3(256), 0, stream>>>(x, gamma, beta, Xn);
    transpose_kernel<<<dim3(HID / 32, DIM / 32, 1), dim3(256), 0, stream>>>(W1, W1t, DIM, HID);
    transpose_kernel<<<dim3(DIM / 32, HID / 32, 1), dim3(256), 0, stream>>>(W2, W2t, HID, DIM);
    transpose_kernel<<<dim3(HID2 / 32, DIM / 32, NLEV), dim3(256), 0, stream>>>(A1, A1t, DIM, HID2);
    transpose_kernel<<<dim3(DIM / 32, HID2 / 32, NLEV), dim3(256), 0, stream>>>(A2, A2t, HID2, DIM);
    routing_kernel<<<dim3(1), dim3(256), 0, stream>>>(levels, lmw, mix, row_index, tile_meta, zbuf);
    gemm1_kernel<<<dim3(ROWS / 128, HID / 128), dim3(256), 0, stream>>>(Xn, W1t, b1, H);
    agemm1_kernel<<<dim3(MAXTILES, HID2 / 128), dim3(256), 0, stream>>>(Xn, A1t, a1b, row_index, tile_meta, (const bf16*)zbuf, HL);
    gemm2_kernel<<<dim3(ROWS / 128, DIM / 128), dim3(256), 0, stream>>>(H, W2t, b2, mix, out);
    agemm2_kernel<<<dim3(MAXTILES, DIM / 128), dim3(256), 0, stream>>>(HL, A2t, a2b, row_index, tile_meta, mix, out);
}

// Round 2
// 342.669 us; speedup vs baseline: 1.0245x; 1.0245x over previous
//
#include <hip/hip_runtime.h>
#include <hip/hip_bf16.h>
#include <math.h>

typedef __bf16 bf16;
typedef __bf16 bf16x8 __attribute__((ext_vector_type(8)));
typedef float f32x4 __attribute__((ext_vector_type(4)));

#define DIM 768
#define HID 3072
#define HID2 1536
#define NLEV 9
#define SEQ 2048
#define ROWS 4096            // BATCH*SEQ
#define MAXPAD 5248          // ROWS + NLEV*128 (rounded)
#define MAXTILES 41          // MAXPAD/128

// ---------------- async global->LDS 16B ----------------
__device__ __forceinline__ void gld16(const void* g, void* l) {
    __builtin_amdgcn_global_load_lds(
        (const __attribute__((address_space(1))) void*)g,
        (__attribute__((address_space(3))) void*)l, 16, 0, 0);
}

// ================= PREP bodies =================

__device__ __forceinline__ void ln_body(int row, float* sm,
                                        const float* __restrict__ x,
                                        const float* __restrict__ gamma,
                                        const float* __restrict__ beta,
                                        bf16* __restrict__ xn) {
    int tid = threadIdx.x;
    const float* xr = x + (size_t)row * DIM;
    float v0 = xr[tid], v1 = xr[tid + 256], v2 = xr[tid + 512];
    float s = v0 + v1 + v2;
    float q = v0 * v0 + v1 * v1 + v2 * v2;
    for (int off = 32; off; off >>= 1) {
        s += __shfl_down(s, off, 64);
        q += __shfl_down(q, off, 64);
    }
    int wv = tid >> 6, ln = tid & 63;
    if (ln == 0) { sm[wv] = s; sm[4 + wv] = q; }
    __syncthreads();
    if (tid == 0) {
        float S = sm[0] + sm[1] + sm[2] + sm[3];
        float Q = sm[4] + sm[5] + sm[6] + sm[7];
        float m = S * (1.0f / DIM);
        float var = Q * (1.0f / DIM) - m * m;
        sm[8] = m;
        sm[9] = rsqrtf(var + 1e-5f);
    }
    __syncthreads();
    float m = sm[8], r = sm[9];
    bf16* xo = xn + (size_t)row * DIM;
    xo[tid]       = (bf16)((v0 - m) * r * gamma[tid]       + beta[tid]);
    xo[tid + 256] = (bf16)((v1 - m) * r * gamma[tid + 256] + beta[tid + 256]);
    xo[tid + 512] = (bf16)((v2 - m) * r * gamma[tid + 512] + beta[tid + 512]);
}

__device__ __forceinline__ void transpose_body(float* sm,
                                               const float* __restrict__ inb,
                                               bf16* __restrict__ outb,
                                               int R, int C, int bx, int by) {
    float (*tile)[33] = (float (*)[33])sm;
    int tx = threadIdx.x & 31, ty = threadIdx.x >> 5;  // ty 0..7
#pragma unroll
    for (int i = 0; i < 4; i++) {
        int r = by * 32 + ty + i * 8;
        tile[ty + i * 8][tx] = inb[(size_t)r * C + bx * 32 + tx];
    }
    __syncthreads();
#pragma unroll
    for (int i = 0; i < 4; i++) {
        int c = bx * 32 + ty + i * 8;
        outb[(size_t)c * R + by * 32 + tx] = (bf16)tile[tx][ty + i * 8];
    }
}

__device__ __forceinline__ void routing_body(float* sm,
                                             const int* __restrict__ levels_info,
                                             const float* __restrict__ lmw,
                                             float* __restrict__ mix,
                                             int* __restrict__ row_index,
                                             int* __restrict__ tile_meta,
                                             float* __restrict__ zbuf) {
    int* cnt = (int*)sm;            // [NLEV]
    int* cur = cnt + NLEV;          // [NLEV]
    int* off = cur + NLEV;          // [NLEV]
    float* mixv = (float*)(off + NLEV);  // [NLEV]
    int tid = threadIdx.x;
    if (tid < NLEV) { cnt[tid] = 0; cur[tid] = 0; }
    __syncthreads();
    for (int s = tid; s < SEQ; s += 256) {
        int d = levels_info[s * 4];
        d = d < 0 ? 0 : (d > 8 ? 8 : d);
        atomicAdd(&cnt[d], 1);
    }
    for (int i = tid; i < MAXPAD; i += 256) row_index[i] = -1;
    if (tid < 16) zbuf[tid] = 0.0f;
    __syncthreads();
    if (tid == 0) {
        float mx = lmw[0];
        for (int l = 1; l < NLEV; l++) mx = fmaxf(mx, lmw[l]);
        float denom = 0.f;
        for (int l = 0; l < NLEV; l++) denom += (float)cnt[l] * expf(lmw[l] - mx);
        float inv = 1.0f / denom;
        int running = 0, t = 0;
        for (int l = 0; l < NLEV; l++) {
            mixv[l] = expf(lmw[l] - mx) * inv;
            off[l] = running;
            int seg = (2 * cnt[l] + 127) & ~127;
            for (int k = 0; k < seg / 128; k++) tile_meta[t++] = l;
            running += seg;
        }
        for (; t < MAXTILES; t++) tile_meta[t] = -1;
    }
    __syncthreads();
    for (int s = tid; s < SEQ; s += 256) {
        int d = levels_info[s * 4];
        d = d < 0 ? 0 : (d > 8 ? 8 : d);
        int p = atomicAdd(&cur[d], 2);
        row_index[off[d] + p]     = s;
        row_index[off[d] + p + 1] = s + SEQ;
        mix[s] = mixv[d];
    }
}

// ---------------- fat prep kernel: routing + LN + all transposes ----------------
// block 0: routing; blocks [1,4097): LN; then W1,W2,A1,A2 transposes.
__global__ __launch_bounds__(256) void prep_kernel(const float* __restrict__ x,
                                                   const int* __restrict__ levels_info,
                                                   const float* __restrict__ gamma,
                                                   const float* __restrict__ beta,
                                                   const float* __restrict__ W1,
                                                   const float* __restrict__ W2,
                                                   const float* __restrict__ A1,
                                                   const float* __restrict__ A2,
                                                   const float* __restrict__ lmw,
                                                   bf16* __restrict__ Xn,
                                                   bf16* __restrict__ W1t,
                                                   bf16* __restrict__ W2t,
                                                   bf16* __restrict__ A1t,
                                                   bf16* __restrict__ A2t,
                                                   float* __restrict__ mix,
                                                   int* __restrict__ row_index,
                                                   int* __restrict__ tile_meta,
                                                   float* __restrict__ zbuf) {
    __shared__ __align__(16) float sm[32 * 33];
    int bid = blockIdx.x;
    if (bid == 0) { routing_body(sm, levels_info, lmw, mix, row_index, tile_meta, zbuf); return; }
    bid -= 1;
    if (bid < ROWS) { ln_body(bid, sm, x, gamma, beta, Xn); return; }
    bid -= ROWS;
    if (bid < 2304) {  // W1: [768,3072] -> W1t [3072,768]
        transpose_body(sm, W1, W1t, DIM, HID, bid % 96, bid / 96);
        return;
    }
    bid -= 2304;
    if (bid < 2304) {  // W2: [3072,768] -> W2t [768,3072]
        transpose_body(sm, W2, W2t, HID, DIM, bid % 24, bid / 24);
        return;
    }
    bid -= 2304;
    if (bid < 10368) {  // A1[lvl]: [768,1536] -> A1t[lvl] [1536,768]
        int bz = bid / 1152, r = bid % 1152;
        transpose_body(sm, A1 + (size_t)bz * DIM * HID2, A1t + (size_t)bz * DIM * HID2,
                       DIM, HID2, r % 48, r / 48);
        return;
    }
    bid -= 10368;
    {   // A2[lvl]: [1536,768] -> A2t[lvl] [768,1536]
        int bz = bid / 1152, r = bid % 1152;
        transpose_body(sm, A2 + (size_t)bz * HID2 * DIM, A2t + (size_t)bz * HID2 * DIM,
                       HID2, DIM, r % 24, r / 24);
    }
}

// ---------------- shared GEMM main loop: C[128,128] tile, BK=32 ----------------
__device__ __forceinline__ void gemm_loop(const bf16* ga0, const bf16* ga1,
                                          int stepa0, int stepa1,
                                          const bf16* gb0, const bf16* gb1, int stepb,
                                          bf16* As, bf16* Bs,
                                          f32x4 (&acc)[4][4], int ktiles) {
    int tid = threadIdx.x;
    int wv = tid >> 6;
    int lane = tid & 63;
    int wm = wv >> 1, wn = wv & 1;
    const bf16* arow = As + ((wm * 64) + (lane & 15)) * 32 + (lane >> 4) * 8;
    const bf16* brow = Bs + ((wn * 64) + (lane & 15)) * 32 + (lane >> 4) * 8;
    for (int kt = 0; kt < ktiles; ++kt) {
        gld16(ga0, As + wv * 512);
        gld16(ga1, As + 2048 + wv * 512);
        gld16(gb0, Bs + wv * 512);
        gld16(gb1, Bs + 2048 + wv * 512);
        ga0 += stepa0; ga1 += stepa1; gb0 += stepb; gb1 += stepb;
        __syncthreads();
        bf16x8 af[4], bfr[4];
#pragma unroll
        for (int i = 0; i < 4; i++) af[i] = *(const bf16x8*)(arow + i * 16 * 32);
#pragma unroll
        for (int j = 0; j < 4; j++) bfr[j] = *(const bf16x8*)(brow + j * 16 * 32);
#pragma unroll
        for (int i = 0; i < 4; i++)
#pragma unroll
            for (int j = 0; j < 4; j++)
                acc[i][j] = __builtin_amdgcn_mfma_f32_16x16x32_bf16(af[i], bfr[j], acc[i][j], 0, 0, 0);
        __syncthreads();
    }
}

#define ACC_INIT(acc) \
    _Pragma("unroll") for (int i = 0; i < 4; i++) \
    _Pragma("unroll") for (int j = 0; j < 4; j++) acc[i][j] = (f32x4){0.f, 0.f, 0.f, 0.f};

// ---------------- mlp1: gemm1 (H=gelu(Xn@W1+b1)) + agemm1 (HL=relu(gather@A1+a1b)) ----------------
__global__ __launch_bounds__(256) void mlp1_kernel(const bf16* __restrict__ Xn,
                                                   const bf16* __restrict__ W1t,
                                                   const float* __restrict__ b1,
                                                   bf16* __restrict__ H,
                                                   const bf16* __restrict__ A1t,
                                                   const float* __restrict__ a1b,
                                                   const int* __restrict__ row_index,
                                                   const int* __restrict__ tile_meta,
                                                   const bf16* __restrict__ zbuf,
                                                   bf16* __restrict__ HL) {
    __shared__ __align__(16) bf16 As[4096], Bs[4096];
    int bid = blockIdx.x, tid = threadIdx.x;
    int r0 = tid >> 2, cg = tid & 3;
    int lane = tid & 63, wv = tid >> 6, wm = wv >> 1, wn = wv & 1;
    f32x4 acc[4][4];
    ACC_INIT(acc);

    if (bid < 768) {
        // ---- gemm1: 32 M-tiles x 24 N-tiles ----
        int mb = bid & 31, nb = bid >> 5;
        const bf16* ga0 = Xn + (size_t)(mb * 128 + r0) * DIM + cg * 8;
        const bf16* ga1 = ga0 + (size_t)64 * DIM;
        const bf16* gb0 = W1t + (size_t)(nb * 128 + r0) * DIM + cg * 8;
        const bf16* gb1 = gb0 + (size_t)64 * DIM;
        gemm_loop(ga0, ga1, 32, 32, gb0, gb1, 32, As, Bs, acc, DIM / 32);
        int rbase = mb * 128 + wm * 64 + ((lane >> 4) << 2);
        int cbase = nb * 128 + wn * 64 + (lane & 15);
#pragma unroll
        for (int j = 0; j < 4; j++) {
            int c = cbase + j * 16;
            float bias = b1[c];
#pragma unroll
            for (int i = 0; i < 4; i++)
#pragma unroll
                for (int r = 0; r < 4; r++) {
                    int row = rbase + i * 16 + r;
                    float v = acc[i][j][r] + bias;
                    float g = 0.5f * v * (1.0f + erff(v * 0.70710678118f));
                    H[(size_t)row * HID + c] = (bf16)g;
                }
        }
    } else {
        // ---- agemm1: 41 tiles x 12 N-tiles ----
        int t2 = bid - 768;
        int t = t2 % MAXTILES, nb = t2 / MAXTILES;
        int lvl = tile_meta[t];
        if (lvl < 0) return;
        int ridx0 = row_index[t * 128 + r0];
        int ridx1 = row_index[t * 128 + 64 + r0];
        const bf16* ga0 = (ridx0 >= 0) ? (Xn + (size_t)ridx0 * DIM + cg * 8) : zbuf;
        const bf16* ga1 = (ridx1 >= 0) ? (Xn + (size_t)ridx1 * DIM + cg * 8) : zbuf;
        int sa0 = (ridx0 >= 0) ? 32 : 0;
        int sa1 = (ridx1 >= 0) ? 32 : 0;
        const bf16* Bl = A1t + (size_t)lvl * HID2 * DIM;
        const bf16* gb0 = Bl + (size_t)(nb * 128 + r0) * DIM + cg * 8;
        const bf16* gb1 = gb0 + (size_t)64 * DIM;
        gemm_loop(ga0, ga1, sa0, sa1, gb0, gb1, 32, As, Bs, acc, DIM / 32);
        int rbase = wm * 64 + ((lane >> 4) << 2);
        int cbase = nb * 128 + wn * 64 + (lane & 15);
#pragma unroll
        for (int j = 0; j < 4; j++) {
            int c = cbase + j * 16;
            float bias = a1b[lvl * HID2 + c];
#pragma unroll
            for (int i = 0; i < 4; i++)
#pragma unroll
                for (int r = 0; r < 4; r++) {
                    int rl = rbase + i * 16 + r;
                    float v = acc[i][j][r] + bias;
                    HL[(size_t)(t * 128 + rl) * HID2 + c] = (bf16)fmaxf(v, 0.0f);
                }
        }
    }
}

// ---------------- mlp2: gemm2 split-K=2 + agemm2, atomicAdd into zeroed out ----------------
__global__ __launch_bounds__(256) void mlp2_kernel(const bf16* __restrict__ H,
                                                   const bf16* __restrict__ W2t,
                                                   const float* __restrict__ b2,
                                                   const float* __restrict__ mix,
                                                   float* __restrict__ out,
                                                   const bf16* __restrict__ HL,
                                                   const bf16* __restrict__ A2t,
                                                   const float* __restrict__ a2b,
                                                   const int* __restrict__ row_index,
                                                   const int* __restrict__ tile_meta) {
    __shared__ __align__(16) bf16 As[4096], Bs[4096];
    int bid = blockIdx.x, tid = threadIdx.x;
    int r0 = tid >> 2, cg = tid & 3;
    int lane = tid & 63, wv = tid >> 6, wm = wv >> 1, wn = wv & 1;
    f32x4 acc[4][4];
    ACC_INIT(acc);

    if (bid < 384) {
        // ---- gemm2: 32 M-tiles x 6 N-tiles x 2 K-splits, K-chunk = 1536 (48 iters) ----
        int mb = bid & 31;
        int rest = bid >> 5;        // 0..11
        int nb = rest % 6;
        int ks = rest / 6;          // 0..1
        const bf16* ga0 = H + (size_t)(mb * 128 + r0) * HID + ks * 1536 + cg * 8;
        const bf16* ga1 = ga0 + (size_t)64 * HID;
        const bf16* gb0 = W2t + (size_t)(nb * 128 + r0) * HID + ks * 1536 + cg * 8;
        const bf16* gb1 = gb0 + (size_t)64 * HID;
        gemm_loop(ga0, ga1, 32, 32, gb0, gb1, 32, As, Bs, acc, 48);
        int rbase = mb * 128 + wm * 64 + ((lane >> 4) << 2);
        int cbase = nb * 128 + wn * 64 + (lane & 15);
#pragma unroll
        for (int j = 0; j < 4; j++) {
            int c = cbase + j * 16;
            float bias = (ks == 0) ? b2[c] : 0.0f;
#pragma unroll
            for (int i = 0; i < 4; i++)
#pragma unroll
                for (int r = 0; r < 4; r++) {
                    int row = rbase + i * 16 + r;
                    float mx = mix[row & (SEQ - 1)];
                    atomicAdd(&out[(size_t)row * DIM + c], (1.0f - mx) * (acc[i][j][r] + bias));
                }
        }
    } else {
        // ---- agemm2: 41 tiles x 6 N-tiles, K = 1536 (48 iters) ----
        int t2 = bid - 384;
        int t = t2 % MAXTILES, nb = t2 / MAXTILES;
        int lvl = tile_meta[t];
        if (lvl < 0) return;
        const bf16* ga0 = HL + (size_t)(t * 128 + r0) * HID2 + cg * 8;
        const bf16* ga1 = ga0 + (size_t)64 * HID2;
        const bf16* Bl = A2t + (size_t)lvl * DIM * HID2;
        const bf16* gb0 = Bl + (size_t)(nb * 128 + r0) * HID2 + cg * 8;
        const bf16* gb1 = gb0 + (size_t)64 * HID2;
        gemm_loop(ga0, ga1, 32, 32, gb0, gb1, 32, As, Bs, acc, HID2 / 32);
        int rbase = wm * 64 + ((lane >> 4) << 2);
        int cbase = nb * 128 + wn * 64 + (lane & 15);
#pragma unroll
        for (int i = 0; i < 4; i++)
#pragma unroll
            for (int r = 0; r < 4; r++) {
                int rl = rbase + i * 16 + r;
                int rg = row_index[t * 128 + rl];
                if (rg >= 0) {
                    float mx = mix[rg & (SEQ - 1)];
#pragma unroll
                    for (int j = 0; j < 4; j++) {
                        int c = cbase + j * 16;
                        atomicAdd(&out[(size_t)rg * DIM + c], mx * (acc[i][j][r] + a2b[lvl * DIM + c]));
                    }
                }
            }
    }
}

// ---------------- launch ----------------
extern "C" void kernel_launch(void* const* d_in, const int* in_sizes, int n_in,
                              void* d_out, int out_size, void* d_ws, size_t ws_size,
                              hipStream_t stream) {
    const float* x    = (const float*)d_in[0];
    const int* levels = (const int*)d_in[1];
    const float* gamma= (const float*)d_in[2];
    const float* beta = (const float*)d_in[3];
    const float* W1   = (const float*)d_in[4];
    const float* b1   = (const float*)d_in[5];
    const float* W2   = (const float*)d_in[6];
    const float* b2   = (const float*)d_in[7];
    const float* A1   = (const float*)d_in[8];
    const float* a1b  = (const float*)d_in[9];
    const float* A2   = (const float*)d_in[10];
    const float* a2b  = (const float*)d_in[11];
    const float* lmw  = (const float*)d_in[12];
    float* out = (float*)d_out;

    char* p = (char*)d_ws;
    auto alloc = [&](size_t bytes) {
        char* r = p;
        p += (bytes + 255) & ~(size_t)255;
        return r;
    };
    bf16* Xn   = (bf16*)alloc((size_t)ROWS * DIM * 2);
    bf16* W1t  = (bf16*)alloc((size_t)HID * DIM * 2);
    bf16* W2t  = (bf16*)alloc((size_t)DIM * HID * 2);
    bf16* A1t  = (bf16*)alloc((size_t)NLEV * HID2 * DIM * 2);
    bf16* A2t  = (bf16*)alloc((size_t)NLEV * DIM * HID2 * 2);
    bf16* H    = (bf16*)alloc((size_t)ROWS * HID * 2);
    bf16* HL   = (bf16*)alloc((size_t)MAXPAD * HID2 * 2);
    float* mix = (float*)alloc(SEQ * 4);
    int* row_index = (int*)alloc(MAXPAD * 4);
    int* tile_meta = (int*)alloc(MAXTILES * 4);
    float* zbuf    = (float*)alloc(64);

    // zero the output for atomic accumulation in mlp2
    hipMemsetAsync(d_out, 0, (size_t)out_size * sizeof(float), stream);

    // prep: routing(1) + LN(4096) + W1(2304) + W2(2304) + A1(10368) + A2(10368)
    prep_kernel<<<dim3(1 + ROWS + 2304 + 2304 + 10368 + 10368), dim3(256), 0, stream>>>(
        x, levels, gamma, beta, W1, W2, A1, A2, lmw,
        Xn, W1t, W2t, A1t, A2t, mix, row_index, tile_meta, zbuf);

    // mlp1: gemm1 (768) + agemm1 (492)
    mlp1_kernel<<<dim3(768 + MAXTILES * 12), dim3(256), 0, stream>>>(
        Xn, W1t, b1, H, A1t, a1b, row_index, tile_meta, (const bf16*)zbuf, HL);

    // mlp2: gemm2 splitK2 (384) + agemm2 (246)
    mlp2_kernel<<<dim3(384 + MAXTILES * 6), dim3(256), 0, stream>>>(
        H, W2t, b2, mix, out, HL, A2t, a2b, row_index, tile_meta);
}

// Round 3
// 295.874 us; speedup vs baseline: 1.1866x; 1.1582x over previous
//
#include <hip/hip_runtime.h>
#include <hip/hip_bf16.h>
#include <math.h>

typedef __bf16 bf16;
typedef __bf16 bf16x4 __attribute__((ext_vector_type(4)));
typedef __bf16 bf16x8 __attribute__((ext_vector_type(8)));
typedef float f32x4 __attribute__((ext_vector_type(4)));

#define DIM 768
#define HID 3072
#define HID2 1536
#define NLEV 9
#define SEQ 2048
#define ROWS 4096            // BATCH*SEQ
#define MAXPAD 5248          // ROWS + NLEV*128 (rounded)
#define MAXTILES 41          // MAXPAD/128

// ---------------- async global->LDS 16B ----------------
__device__ __forceinline__ void gld16(const void* g, void* l) {
    __builtin_amdgcn_global_load_lds(
        (const __attribute__((address_space(1))) void*)g,
        (__attribute__((address_space(3))) void*)l, 16, 0, 0);
}

// ================= PREP bodies =================

__device__ __forceinline__ void ln_body(int row, float* sm,
                                        const float* __restrict__ x,
                                        const float* __restrict__ gamma,
                                        const float* __restrict__ beta,
                                        bf16* __restrict__ xn) {
    int tid = threadIdx.x;
    const float* xr = x + (size_t)row * DIM;
    float v0 = xr[tid], v1 = xr[tid + 256], v2 = xr[tid + 512];
    float s = v0 + v1 + v2;
    float q = v0 * v0 + v1 * v1 + v2 * v2;
    for (int off = 32; off; off >>= 1) {
        s += __shfl_down(s, off, 64);
        q += __shfl_down(q, off, 64);
    }
    int wv = tid >> 6, ln = tid & 63;
    if (ln == 0) { sm[wv] = s; sm[4 + wv] = q; }
    __syncthreads();
    if (tid == 0) {
        float S = sm[0] + sm[1] + sm[2] + sm[3];
        float Q = sm[4] + sm[5] + sm[6] + sm[7];
        float m = S * (1.0f / DIM);
        float var = Q * (1.0f / DIM) - m * m;
        sm[8] = m;
        sm[9] = rsqrtf(var + 1e-5f);
    }
    __syncthreads();
    float m = sm[8], r = sm[9];
    bf16* xo = xn + (size_t)row * DIM;
    xo[tid]       = (bf16)((v0 - m) * r * gamma[tid]       + beta[tid]);
    xo[tid + 256] = (bf16)((v1 - m) * r * gamma[tid + 256] + beta[tid + 256]);
    xo[tid + 512] = (bf16)((v2 - m) * r * gamma[tid + 512] + beta[tid + 512]);
}

__device__ __forceinline__ void transpose_body(float* sm,
                                               const float* __restrict__ inb,
                                               bf16* __restrict__ outb,
                                               int R, int C, int bx, int by) {
    float (*tile)[33] = (float (*)[33])sm;
    int tx = threadIdx.x & 31, ty = threadIdx.x >> 5;  // ty 0..7
#pragma unroll
    for (int i = 0; i < 4; i++) {
        int r = by * 32 + ty + i * 8;
        tile[ty + i * 8][tx] = inb[(size_t)r * C + bx * 32 + tx];
    }
    __syncthreads();
#pragma unroll
    for (int i = 0; i < 4; i++) {
        int c = bx * 32 + ty + i * 8;
        outb[(size_t)c * R + by * 32 + tx] = (bf16)tile[tx][ty + i * 8];
    }
}

__device__ __forceinline__ void routing_body(float* sm,
                                             const int* __restrict__ levels_info,
                                             const float* __restrict__ lmw,
                                             float* __restrict__ mix,
                                             int* __restrict__ row_index,
                                             int* __restrict__ tile_meta,
                                             float* __restrict__ zbuf) {
    int* cnt = (int*)sm;            // [NLEV]
    int* cur = cnt + NLEV;          // [NLEV]
    int* off = cur + NLEV;          // [NLEV]
    float* mixv = (float*)(off + NLEV);  // [NLEV]
    int tid = threadIdx.x;
    if (tid < NLEV) { cnt[tid] = 0; cur[tid] = 0; }
    __syncthreads();
    for (int s = tid; s < SEQ; s += 256) {
        int d = levels_info[s * 4];
        d = d < 0 ? 0 : (d > 8 ? 8 : d);
        atomicAdd(&cnt[d], 1);
    }
    for (int i = tid; i < MAXPAD; i += 256) row_index[i] = -1;
    if (tid < 16) zbuf[tid] = 0.0f;
    __syncthreads();
    if (tid == 0) {
        float mx = lmw[0];
        for (int l = 1; l < NLEV; l++) mx = fmaxf(mx, lmw[l]);
        float denom = 0.f;
        for (int l = 0; l < NLEV; l++) denom += (float)cnt[l] * expf(lmw[l] - mx);
        float inv = 1.0f / denom;
        int running = 0, t = 0;
        for (int l = 0; l < NLEV; l++) {
            mixv[l] = expf(lmw[l] - mx) * inv;
            off[l] = running;
            int seg = (2 * cnt[l] + 127) & ~127;
            for (int k = 0; k < seg / 128; k++) tile_meta[t++] = l;
            running += seg;
        }
        for (; t < MAXTILES; t++) tile_meta[t] = -1;
    }
    __syncthreads();
    for (int s = tid; s < SEQ; s += 256) {
        int d = levels_info[s * 4];
        d = d < 0 ? 0 : (d > 8 ? 8 : d);
        int p = atomicAdd(&cur[d], 2);
        row_index[off[d] + p]     = s;
        row_index[off[d] + p + 1] = s + SEQ;
        mix[s] = mixv[d];
    }
}

// ---------------- fat prep kernel: routing + LN + all transposes ----------------
__global__ __launch_bounds__(256) void prep_kernel(const float* __restrict__ x,
                                                   const int* __restrict__ levels_info,
                                                   const float* __restrict__ gamma,
                                                   const float* __restrict__ beta,
                                                   const float* __restrict__ W1,
                                                   const float* __restrict__ W2,
                                                   const float* __restrict__ A1,
                                                   const float* __restrict__ A2,
                                                   const float* __restrict__ lmw,
                                                   bf16* __restrict__ Xn,
                                                   bf16* __restrict__ W1t,
                                                   bf16* __restrict__ W2t,
                                                   bf16* __restrict__ A1t,
                                                   bf16* __restrict__ A2t,
                                                   float* __restrict__ mix,
                                                   int* __restrict__ row_index,
                                                   int* __restrict__ tile_meta,
                                                   float* __restrict__ zbuf) {
    __shared__ __align__(16) float sm[32 * 33];
    int bid = blockIdx.x;
    if (bid == 0) { routing_body(sm, levels_info, lmw, mix, row_index, tile_meta, zbuf); return; }
    bid -= 1;
    if (bid < ROWS) { ln_body(bid, sm, x, gamma, beta, Xn); return; }
    bid -= ROWS;
    if (bid < 2304) {  // W1: [768,3072] -> W1t [3072,768]
        transpose_body(sm, W1, W1t, DIM, HID, bid % 96, bid / 96);
        return;
    }
    bid -= 2304;
    if (bid < 2304) {  // W2: [3072,768] -> W2t [768,3072]
        transpose_body(sm, W2, W2t, HID, DIM, bid % 24, bid / 24);
        return;
    }
    bid -= 2304;
    if (bid < 10368) {  // A1[lvl]: [768,1536] -> A1t[lvl] [1536,768]
        int bz = bid / 1152, r = bid % 1152;
        transpose_body(sm, A1 + (size_t)bz * DIM * HID2, A1t + (size_t)bz * DIM * HID2,
                       DIM, HID2, r % 48, r / 48);
        return;
    }
    bid -= 10368;
    {   // A2[lvl]: [1536,768] -> A2t[lvl] [768,1536]
        int bz = bid / 1152, r = bid % 1152;
        transpose_body(sm, A2 + (size_t)bz * HID2 * DIM, A2t + (size_t)bz * HID2 * DIM,
                       HID2, DIM, r % 24, r / 24);
    }
}

// ---------------- double-buffered GEMM main loop: C[128,128] tile, BK=32 ----------------
// As/Bs are 2*4096 bf16 each (two 128x32 buffers). One barrier per iteration;
// prefetch of tile k+1 issued before MFMA on tile k, drained at next barrier.
__device__ __forceinline__ void gemm_loop_db(const bf16* ga0, const bf16* ga1,
                                             int stepa0, int stepa1,
                                             const bf16* gb0, const bf16* gb1, int stepb,
                                             bf16* As, bf16* Bs,
                                             f32x4 (&acc)[4][4], int ktiles) {
    int tid = threadIdx.x;
    int wv = tid >> 6;
    int lane = tid & 63;
    int wm = wv >> 1, wn = wv & 1;
    int aoff = ((wm * 64) + (lane & 15)) * 32 + (lane >> 4) * 8;
    int boff = ((wn * 64) + (lane & 15)) * 32 + (lane >> 4) * 8;
    // prologue: stage tile 0 into buffer 0
    gld16(ga0, As + wv * 512);
    gld16(ga1, As + 2048 + wv * 512);
    gld16(gb0, Bs + wv * 512);
    gld16(gb1, Bs + 2048 + wv * 512);
    ga0 += stepa0; ga1 += stepa1; gb0 += stepb; gb1 += stepb;
    for (int kt = 0; kt < ktiles; ++kt) {
        __syncthreads();  // buffer (kt&1) fully staged; prior reads of other buffer done
        int cur = (kt & 1) << 12;      // 0 or 4096
        int nxt = cur ^ 4096;
        if (kt + 1 < ktiles) {
            gld16(ga0, As + nxt + wv * 512);
            gld16(ga1, As + nxt + 2048 + wv * 512);
            gld16(gb0, Bs + nxt + wv * 512);
            gld16(gb1, Bs + nxt + 2048 + wv * 512);
            ga0 += stepa0; ga1 += stepa1; gb0 += stepb; gb1 += stepb;
        }
        bf16x8 af[4], bfr[4];
#pragma unroll
        for (int i = 0; i < 4; i++) af[i] = *(const bf16x8*)(As + cur + aoff + i * 512);
#pragma unroll
        for (int j = 0; j < 4; j++) bfr[j] = *(const bf16x8*)(Bs + cur + boff + j * 512);
#pragma unroll
        for (int i = 0; i < 4; i++)
#pragma unroll
            for (int j = 0; j < 4; j++)
                acc[i][j] = __builtin_amdgcn_mfma_f32_16x16x32_bf16(af[i], bfr[j], acc[i][j], 0, 0, 0);
    }
}

#define ACC_INIT(acc) \
    _Pragma("unroll") for (int i = 0; i < 4; i++) \
    _Pragma("unroll") for (int j = 0; j < 4; j++) acc[i][j] = (f32x4){0.f, 0.f, 0.f, 0.f};

// ---------------- mlp1: gemm1 (H=gelu(Xn@W1+b1)) + agemm1 (HL=relu(gather@A1+a1b)) ----------------
__global__ __launch_bounds__(256) void mlp1_kernel(const bf16* __restrict__ Xn,
                                                   const bf16* __restrict__ W1t,
                                                   const float* __restrict__ b1,
                                                   bf16* __restrict__ H,
                                                   const bf16* __restrict__ A1t,
                                                   const float* __restrict__ a1b,
                                                   const int* __restrict__ row_index,
                                                   const int* __restrict__ tile_meta,
                                                   const bf16* __restrict__ zbuf,
                                                   bf16* __restrict__ HL) {
    __shared__ __align__(16) bf16 As[8192], Bs[8192];
    int bid = blockIdx.x, tid = threadIdx.x;
    int r0 = tid >> 2, cg = tid & 3;
    int lane = tid & 63, wv = tid >> 6, wm = wv >> 1, wn = wv & 1;
    f32x4 acc[4][4];
    ACC_INIT(acc);

    if (bid < 768) {
        // ---- gemm1: 32 M-tiles x 24 N-tiles ----
        int mb = bid & 31, nb = bid >> 5;
        const bf16* ga0 = Xn + (size_t)(mb * 128 + r0) * DIM + cg * 8;
        const bf16* ga1 = ga0 + (size_t)64 * DIM;
        const bf16* gb0 = W1t + (size_t)(nb * 128 + r0) * DIM + cg * 8;
        const bf16* gb1 = gb0 + (size_t)64 * DIM;
        gemm_loop_db(ga0, ga1, 32, 32, gb0, gb1, 32, As, Bs, acc, DIM / 32);
        int rbase = mb * 128 + wm * 64 + ((lane >> 4) << 2);
        int cbase = nb * 128 + wn * 64 + (lane & 15);
#pragma unroll
        for (int j = 0; j < 4; j++) {
            int c = cbase + j * 16;
            float bias = b1[c];
#pragma unroll
            for (int i = 0; i < 4; i++)
#pragma unroll
                for (int r = 0; r < 4; r++) {
                    int row = rbase + i * 16 + r;
                    float v = acc[i][j][r] + bias;
                    float g = 0.5f * v * (1.0f + erff(v * 0.70710678118f));
                    H[(size_t)row * HID + c] = (bf16)g;
                }
        }
    } else {
        // ---- agemm1: 41 tiles x 12 N-tiles ----
        int t2 = bid - 768;
        int t = t2 % MAXTILES, nb = t2 / MAXTILES;
        int lvl = tile_meta[t];
        if (lvl < 0) return;
        int ridx0 = row_index[t * 128 + r0];
        int ridx1 = row_index[t * 128 + 64 + r0];
        const bf16* ga0 = (ridx0 >= 0) ? (Xn + (size_t)ridx0 * DIM + cg * 8) : zbuf;
        const bf16* ga1 = (ridx1 >= 0) ? (Xn + (size_t)ridx1 * DIM + cg * 8) : zbuf;
        int sa0 = (ridx0 >= 0) ? 32 : 0;
        int sa1 = (ridx1 >= 0) ? 32 : 0;
        const bf16* Bl = A1t + (size_t)lvl * HID2 * DIM;
        const bf16* gb0 = Bl + (size_t)(nb * 128 + r0) * DIM + cg * 8;
        const bf16* gb1 = gb0 + (size_t)64 * DIM;
        gemm_loop_db(ga0, ga1, sa0, sa1, gb0, gb1, 32, As, Bs, acc, DIM / 32);
        int rbase = wm * 64 + ((lane >> 4) << 2);
        int cbase = nb * 128 + wn * 64 + (lane & 15);
#pragma unroll
        for (int j = 0; j < 4; j++) {
            int c = cbase + j * 16;
            float bias = a1b[lvl * HID2 + c];
#pragma unroll
            for (int i = 0; i < 4; i++)
#pragma unroll
                for (int r = 0; r < 4; r++) {
                    int rl = rbase + i * 16 + r;
                    float v = acc[i][j][r] + bias;
                    HL[(size_t)(t * 128 + rl) * HID2 + c] = (bf16)fmaxf(v, 0.0f);
                }
        }
    }
}

// ---------------- mlp2: gemm2 split-K=2 -> bf16 partials; agemm2 -> bf16 row-space buffer ----------------
__global__ __launch_bounds__(256) void mlp2_kernel(const bf16* __restrict__ H,
                                                   const bf16* __restrict__ W2t,
                                                   bf16* __restrict__ part,   // [2][ROWS*DIM]
                                                   const bf16* __restrict__ HL,
                                                   const bf16* __restrict__ A2t,
                                                   const float* __restrict__ a2b,
                                                   const int* __restrict__ row_index,
                                                   const int* __restrict__ tile_meta,
                                                   bf16* __restrict__ apart) { // [ROWS*DIM]
    __shared__ __align__(16) bf16 As[8192], Bs[8192];
    int bid = blockIdx.x, tid = threadIdx.x;
    int r0 = tid >> 2, cg = tid & 3;
    int lane = tid & 63, wv = tid >> 6, wm = wv >> 1, wn = wv & 1;
    f32x4 acc[4][4];
    ACC_INIT(acc);

    if (bid < 384) {
        // ---- gemm2: 32 M-tiles x 6 N-tiles x 2 K-splits, K-chunk = 1536 (48 iters) ----
        int mb = bid & 31;
        int rest = bid >> 5;        // 0..11
        int nb = rest % 6;
        int ks = rest / 6;          // 0..1
        const bf16* ga0 = H + (size_t)(mb * 128 + r0) * HID + ks * 1536 + cg * 8;
        const bf16* ga1 = ga0 + (size_t)64 * HID;
        const bf16* gb0 = W2t + (size_t)(nb * 128 + r0) * HID + ks * 1536 + cg * 8;
        const bf16* gb1 = gb0 + (size_t)64 * HID;
        gemm_loop_db(ga0, ga1, 32, 32, gb0, gb1, 32, As, Bs, acc, 48);
        bf16* pk = part + (size_t)ks * ROWS * DIM;
        int rbase = mb * 128 + wm * 64 + ((lane >> 4) << 2);
        int cbase = nb * 128 + wn * 64 + (lane & 15);
#pragma unroll
        for (int j = 0; j < 4; j++) {
            int c = cbase + j * 16;
#pragma unroll
            for (int i = 0; i < 4; i++)
#pragma unroll
                for (int r = 0; r < 4; r++) {
                    int row = rbase + i * 16 + r;
                    pk[(size_t)row * DIM + c] = (bf16)acc[i][j][r];
                }
        }
    } else {
        // ---- agemm2: 41 tiles x 6 N-tiles, K = 1536 (48 iters) ----
        int t2 = bid - 384;
        int t = t2 % MAXTILES, nb = t2 / MAXTILES;
        int lvl = tile_meta[t];
        if (lvl < 0) return;
        const bf16* ga0 = HL + (size_t)(t * 128 + r0) * HID2 + cg * 8;
        const bf16* ga1 = ga0 + (size_t)64 * HID2;
        const bf16* Bl = A2t + (size_t)lvl * DIM * HID2;
        const bf16* gb0 = Bl + (size_t)(nb * 128 + r0) * HID2 + cg * 8;
        const bf16* gb1 = gb0 + (size_t)64 * HID2;
        gemm_loop_db(ga0, ga1, 32, 32, gb0, gb1, 32, As, Bs, acc, HID2 / 32);
        int rbase = wm * 64 + ((lane >> 4) << 2);
        int cbase = nb * 128 + wn * 64 + (lane & 15);
#pragma unroll
        for (int i = 0; i < 4; i++)
#pragma unroll
            for (int r = 0; r < 4; r++) {
                int rl = rbase + i * 16 + r;
                int rg = row_index[t * 128 + rl];
                if (rg >= 0) {
#pragma unroll
                    for (int j = 0; j < 4; j++) {
                        int c = cbase + j * 16;
                        apart[(size_t)rg * DIM + c] = (bf16)(acc[i][j][r] + a2b[lvl * DIM + c]);
                    }
                }
            }
    }
}

// ---------------- combine: out = (1-mix)*(p0+p1+b2) + mix*apart ----------------
__global__ __launch_bounds__(256) void combine_kernel(const bf16* __restrict__ part,
                                                      const bf16* __restrict__ apart,
                                                      const float* __restrict__ b2,
                                                      const float* __restrict__ mix,
                                                      float* __restrict__ out) {
    int i = blockIdx.x * 256 + threadIdx.x;
    int base = i * 4;
    int row = base / DIM;
    int c = base - row * DIM;
    float mx = mix[row & (SEQ - 1)];
    bf16x4 p0 = *(const bf16x4*)(part + base);
    bf16x4 p1 = *(const bf16x4*)(part + (size_t)ROWS * DIM + base);
    bf16x4 ap = *(const bf16x4*)(apart + base);
    float4 o;
    float* po = &o.x;
#pragma unroll
    for (int k = 0; k < 4; k++) {
        float main_v = (float)p0[k] + (float)p1[k] + b2[c + k];
        po[k] = (1.0f - mx) * main_v + mx * (float)ap[k];
    }
    *(float4*)(out + base) = o;
}

// ---------------- launch ----------------
extern "C" void kernel_launch(void* const* d_in, const int* in_sizes, int n_in,
                              void* d_out, int out_size, void* d_ws, size_t ws_size,
                              hipStream_t stream) {
    const float* x    = (const float*)d_in[0];
    const int* levels = (const int*)d_in[1];
    const float* gamma= (const float*)d_in[2];
    const float* beta = (const float*)d_in[3];
    const float* W1   = (const float*)d_in[4];
    const float* b1   = (const float*)d_in[5];
    const float* W2   = (const float*)d_in[6];
    const float* b2   = (const float*)d_in[7];
    const float* A1   = (const float*)d_in[8];
    const float* a1b  = (const float*)d_in[9];
    const float* A2   = (const float*)d_in[10];
    const float* a2b  = (const float*)d_in[11];
    const float* lmw  = (const float*)d_in[12];
    float* out = (float*)d_out;

    char* p = (char*)d_ws;
    auto alloc = [&](size_t bytes) {
        char* r = p;
        p += (bytes + 255) & ~(size_t)255;
        return r;
    };
    bf16* Xn   = (bf16*)alloc((size_t)ROWS * DIM * 2);
    bf16* W1t  = (bf16*)alloc((size_t)HID * DIM * 2);
    bf16* W2t  = (bf16*)alloc((size_t)DIM * HID * 2);
    bf16* A1t  = (bf16*)alloc((size_t)NLEV * HID2 * DIM * 2);
    bf16* A2t  = (bf16*)alloc((size_t)NLEV * DIM * HID2 * 2);
    bf16* H    = (bf16*)alloc((size_t)ROWS * HID * 2);
    bf16* HL   = (bf16*)alloc((size_t)MAXPAD * HID2 * 2);
    bf16* part = (bf16*)alloc((size_t)2 * ROWS * DIM * 2);
    bf16* apart= (bf16*)alloc((size_t)ROWS * DIM * 2);
    float* mix = (float*)alloc(SEQ * 4);
    int* row_index = (int*)alloc(MAXPAD * 4);
    int* tile_meta = (int*)alloc(MAXTILES * 4);
    float* zbuf    = (float*)alloc(64);

    // prep: routing(1) + LN(4096) + W1(2304) + W2(2304) + A1(10368) + A2(10368)
    prep_kernel<<<dim3(1 + ROWS + 2304 + 2304 + 10368 + 10368), dim3(256), 0, stream>>>(
        x, levels, gamma, beta, W1, W2, A1, A2, lmw,
        Xn, W1t, W2t, A1t, A2t, mix, row_index, tile_meta, zbuf);

    // mlp1: gemm1 (768) + agemm1 (492)
    mlp1_kernel<<<dim3(768 + MAXTILES * 12), dim3(256), 0, stream>>>(
        Xn, W1t, b1, H, A1t, a1b, row_index, tile_meta, (const bf16*)zbuf, HL);

    // mlp2: gemm2 splitK2 (384) + agemm2 (246) -> partial buffers, no atomics
    mlp2_kernel<<<dim3(384 + MAXTILES * 6), dim3(256), 0, stream>>>(
        H, W2t, part, HL, A2t, a2b, row_index, tile_meta, apart);

    // combine: blend main + adapter into out
    combine_kernel<<<dim3(ROWS * DIM / 1024), dim3(256), 0, stream>>>(
        part, apart, b2, mix, out);
}

// Round 4
// 292.503 us; speedup vs baseline: 1.2002x; 1.0115x over previous
//
#include <hip/hip_runtime.h>
#include <hip/hip_bf16.h>
#include <math.h>

typedef __bf16 bf16;
typedef __bf16 bf16x4 __attribute__((ext_vector_type(4)));
typedef __bf16 bf16x8 __attribute__((ext_vector_type(8)));
typedef float f32x4 __attribute__((ext_vector_type(4)));

#define DIM 768
#define HID 3072
#define HID2 1536
#define NLEV 9
#define SEQ 2048
#define ROWS 4096            // BATCH*SEQ
#define MAXPAD 5248          // ROWS + NLEV*128 (rounded)
#define MAXTILES 41          // MAXPAD/128

// ---------------- async global->LDS 16B ----------------
__device__ __forceinline__ void gld16(const void* g, void* l) {
    __builtin_amdgcn_global_load_lds(
        (const __attribute__((address_space(1))) void*)g,
        (__attribute__((address_space(3))) void*)l, 16, 0, 0);
}

// ================= PREP bodies =================

__device__ __forceinline__ void ln_body(int row, float* sm,
                                        const float* __restrict__ x,
                                        const float* __restrict__ gamma,
                                        const float* __restrict__ beta,
                                        bf16* __restrict__ xn) {
    int tid = threadIdx.x;
    const float* xr = x + (size_t)row * DIM;
    float v0 = xr[tid], v1 = xr[tid + 256], v2 = xr[tid + 512];
    float s = v0 + v1 + v2;
    float q = v0 * v0 + v1 * v1 + v2 * v2;
    for (int off = 32; off; off >>= 1) {
        s += __shfl_down(s, off, 64);
        q += __shfl_down(q, off, 64);
    }
    int wv = tid >> 6, ln = tid & 63;
    if (ln == 0) { sm[wv] = s; sm[4 + wv] = q; }
    __syncthreads();
    if (tid == 0) {
        float S = sm[0] + sm[1] + sm[2] + sm[3];
        float Q = sm[4] + sm[5] + sm[6] + sm[7];
        float m = S * (1.0f / DIM);
        float var = Q * (1.0f / DIM) - m * m;
        sm[8] = m;
        sm[9] = rsqrtf(var + 1e-5f);
    }
    __syncthreads();
    float m = sm[8], r = sm[9];
    bf16* xo = xn + (size_t)row * DIM;
    xo[tid]       = (bf16)((v0 - m) * r * gamma[tid]       + beta[tid]);
    xo[tid + 256] = (bf16)((v1 - m) * r * gamma[tid + 256] + beta[tid + 256]);
    xo[tid + 512] = (bf16)((v2 - m) * r * gamma[tid + 512] + beta[tid + 512]);
}

// 64x64 tile transpose: fp32 [R][C] -> bf16 [C][R]. sm = 64*65 floats.
__device__ __forceinline__ void transpose_body64(float* sm,
                                                 const float* __restrict__ inb,
                                                 bf16* __restrict__ outb,
                                                 int R, int C, int bx, int by) {
    int tid = threadIdx.x;
    int ty = tid >> 4;            // 0..15
    int tx4 = (tid & 15) * 4;     // col within tile, step 4
#pragma unroll
    for (int p = 0; p < 4; p++) {
        int rloc = p * 16 + ty;
        int row = by * 64 + rloc;
        float4 v = *(const float4*)(inb + (size_t)row * C + bx * 64 + tx4);
        sm[rloc * 65 + tx4 + 0] = v.x;
        sm[rloc * 65 + tx4 + 1] = v.y;
        sm[rloc * 65 + tx4 + 2] = v.z;
        sm[rloc * 65 + tx4 + 3] = v.w;
    }
    __syncthreads();
    int ch = tid & 7;             // 16B chunk along R
    int ocb = tid >> 3;           // 0..31
#pragma unroll
    for (int p = 0; p < 2; p++) {
        int oc = p * 32 + ocb;    // col of tile = out row
        bf16x8 tmp;
#pragma unroll
        for (int k = 0; k < 8; k++) tmp[k] = (bf16)sm[(ch * 8 + k) * 65 + oc];
        *(bf16x8*)(outb + (size_t)(bx * 64 + oc) * R + by * 64 + ch * 8) = tmp;
    }
}

__device__ __forceinline__ void routing_body(float* sm,
                                             const int* __restrict__ levels_info,
                                             const float* __restrict__ lmw,
                                             float* __restrict__ mix,
                                             int* __restrict__ row_index,
                                             int* __restrict__ tile_meta,
                                             float* __restrict__ zbuf) {
    int* cnt = (int*)sm;            // [NLEV]
    int* cur = cnt + NLEV;          // [NLEV]
    int* off = cur + NLEV;          // [NLEV]
    float* mixv = (float*)(off + NLEV);  // [NLEV]
    int tid = threadIdx.x;
    if (tid < NLEV) { cnt[tid] = 0; cur[tid] = 0; }
    __syncthreads();
    for (int s = tid; s < SEQ; s += 256) {
        int d = levels_info[s * 4];
        d = d < 0 ? 0 : (d > 8 ? 8 : d);
        atomicAdd(&cnt[d], 1);
    }
    for (int i = tid; i < MAXPAD; i += 256) row_index[i] = -1;
    if (tid < 16) zbuf[tid] = 0.0f;
    __syncthreads();
    if (tid == 0) {
        float mx = lmw[0];
        for (int l = 1; l < NLEV; l++) mx = fmaxf(mx, lmw[l]);
        float denom = 0.f;
        for (int l = 0; l < NLEV; l++) denom += (float)cnt[l] * expf(lmw[l] - mx);
        float inv = 1.0f / denom;
        int running = 0, t = 0;
        for (int l = 0; l < NLEV; l++) {
            mixv[l] = expf(lmw[l] - mx) * inv;
            off[l] = running;
            int seg = (2 * cnt[l] + 127) & ~127;
            for (int k = 0; k < seg / 128; k++) tile_meta[t++] = l;
            running += seg;
        }
        for (; t < MAXTILES; t++) tile_meta[t] = -1;
    }
    __syncthreads();
    for (int s = tid; s < SEQ; s += 256) {
        int d = levels_info[s * 4];
        d = d < 0 ? 0 : (d > 8 ? 8 : d);
        int p = atomicAdd(&cur[d], 2);
        row_index[off[d] + p]     = s;
        row_index[off[d] + p + 1] = s + SEQ;
        mix[s] = mixv[d];
    }
}

// ---------------- fat prep kernel: routing + LN + all transposes ----------------
__global__ __launch_bounds__(256) void prep_kernel(const float* __restrict__ x,
                                                   const int* __restrict__ levels_info,
                                                   const float* __restrict__ gamma,
                                                   const float* __restrict__ beta,
                                                   const float* __restrict__ W1,
                                                   const float* __restrict__ W2,
                                                   const float* __restrict__ A1,
                                                   const float* __restrict__ A2,
                                                   const float* __restrict__ lmw,
                                                   bf16* __restrict__ Xn,
                                                   bf16* __restrict__ W1t,
                                                   bf16* __restrict__ W2t,
                                                   bf16* __restrict__ A1t,
                                                   bf16* __restrict__ A2t,
                                                   float* __restrict__ mix,
                                                   int* __restrict__ row_index,
                                                   int* __restrict__ tile_meta,
                                                   float* __restrict__ zbuf) {
    __shared__ __align__(16) float sm[64 * 65];
    int bid = blockIdx.x;
    if (bid == 0) { routing_body(sm, levels_info, lmw, mix, row_index, tile_meta, zbuf); return; }
    bid -= 1;
    if (bid < ROWS) { ln_body(bid, sm, x, gamma, beta, Xn); return; }
    bid -= ROWS;
    if (bid < 576) {  // W1 [768,3072] -> [3072,768]: 12 by x 48 bx
        transpose_body64(sm, W1, W1t, DIM, HID, bid % 48, bid / 48);
        return;
    }
    bid -= 576;
    if (bid < 576) {  // W2 [3072,768] -> [768,3072]: 48 by x 12 bx
        transpose_body64(sm, W2, W2t, HID, DIM, bid % 12, bid / 12);
        return;
    }
    bid -= 576;
    if (bid < 2592) {  // A1[lvl] [768,1536] -> [1536,768]: 12 by x 24 bx
        int bz = bid / 288, r = bid % 288;
        transpose_body64(sm, A1 + (size_t)bz * DIM * HID2, A1t + (size_t)bz * DIM * HID2,
                         DIM, HID2, r % 24, r / 24);
        return;
    }
    bid -= 2592;
    {   // A2[lvl] [1536,768] -> [768,1536]: 24 by x 12 bx
        int bz = bid / 288, r = bid % 288;
        transpose_body64(sm, A2 + (size_t)bz * HID2 * DIM, A2t + (size_t)bz * HID2 * DIM,
                         HID2, DIM, r % 12, r / 12);
    }
}

// ---------------- double-buffered GEMM main loop, XOR-swizzled LDS ----------------
// LDS logical layout [128 rows][4 chunks of 8 bf16]; chunk stored at s = g ^ ((row>>1)&3).
// Producer lanes fetch global chunk g = (l&3) ^ ((l>>3)&3) so the linear lane->LDS
// mapping of global_load_lds lands data at the swizzled position.
__device__ __forceinline__ void gemm_loop_db(const bf16* ga0, const bf16* ga1,
                                             int stepa0, int stepa1,
                                             const bf16* gb0, const bf16* gb1, int stepb,
                                             bf16* As, bf16* Bs,
                                             f32x4 (&acc)[4][4], int ktiles) {
    int tid = threadIdx.x;
    int wv = tid >> 6;
    int lane = tid & 63;
    int wm = wv >> 1, wn = wv & 1;
    int swz = (lane >> 1) & 3;                       // ((row)&7)>>1 for row=lane&15
    int achunk = ((lane >> 4) ^ swz) * 8;
    int aoff = ((wm * 64) + (lane & 15)) * 32 + achunk;
    int boff = ((wn * 64) + (lane & 15)) * 32 + achunk;
    // prologue: stage tile 0 into buffer 0
    gld16(ga0, As + wv * 512);
    gld16(ga1, As + 2048 + wv * 512);
    gld16(gb0, Bs + wv * 512);
    gld16(gb1, Bs + 2048 + wv * 512);
    ga0 += stepa0; ga1 += stepa1; gb0 += stepb; gb1 += stepb;
    for (int kt = 0; kt < ktiles; ++kt) {
        __syncthreads();  // buffer (kt&1) fully staged; prior reads of other buffer done
        int cur = (kt & 1) << 12;      // 0 or 4096 elements
        int nxt = cur ^ 4096;
        if (kt + 1 < ktiles) {
            gld16(ga0, As + nxt + wv * 512);
            gld16(ga1, As + nxt + 2048 + wv * 512);
            gld16(gb0, Bs + nxt + wv * 512);
            gld16(gb1, Bs + nxt + 2048 + wv * 512);
            ga0 += stepa0; ga1 += stepa1; gb0 += stepb; gb1 += stepb;
        }
        bf16x8 af[4], bfr[4];
#pragma unroll
        for (int i = 0; i < 4; i++) af[i] = *(const bf16x8*)(As + cur + aoff + i * 512);
#pragma unroll
        for (int j = 0; j < 4; j++) bfr[j] = *(const bf16x8*)(Bs + cur + boff + j * 512);
#pragma unroll
        for (int i = 0; i < 4; i++)
#pragma unroll
            for (int j = 0; j < 4; j++)
                acc[i][j] = __builtin_amdgcn_mfma_f32_16x16x32_bf16(af[i], bfr[j], acc[i][j], 0, 0, 0);
    }
}

#define ACC_INIT(acc) \
    _Pragma("unroll") for (int i = 0; i < 4; i++) \
    _Pragma("unroll") for (int j = 0; j < 4; j++) acc[i][j] = (f32x4){0.f, 0.f, 0.f, 0.f};

// producer-side swizzled chunk index for global fetch
#define SWZ_CG(tid) (((tid) & 3) ^ (((tid) >> 3) & 3))

// ---------------- mlp1: gemm1 (H=gelu(Xn@W1+b1)) + agemm1 (HL=relu(gather@A1+a1b)) ----------------
__global__ __launch_bounds__(256) void mlp1_kernel(const bf16* __restrict__ Xn,
                                                   const bf16* __restrict__ W1t,
                                                   const float* __restrict__ b1,
                                                   bf16* __restrict__ H,
                                                   const bf16* __restrict__ A1t,
                                                   const float* __restrict__ a1b,
                                                   const int* __restrict__ row_index,
                                                   const int* __restrict__ tile_meta,
                                                   const bf16* __restrict__ zbuf,
                                                   bf16* __restrict__ HL) {
    __shared__ __align__(16) bf16 As[8192], Bs[8192];
    int bid = blockIdx.x, tid = threadIdx.x;
    int r0 = tid >> 2, cg = SWZ_CG(tid);
    int lane = tid & 63, wv = tid >> 6, wm = wv >> 1, wn = wv & 1;
    f32x4 acc[4][4];
    ACC_INIT(acc);

    if (bid < 768) {
        // ---- gemm1: 32 M-tiles x 24 N-tiles ----
        int mb = bid & 31, nb = bid >> 5;
        const bf16* ga0 = Xn + (size_t)(mb * 128 + r0) * DIM + cg * 8;
        const bf16* ga1 = ga0 + (size_t)64 * DIM;
        const bf16* gb0 = W1t + (size_t)(nb * 128 + r0) * DIM + cg * 8;
        const bf16* gb1 = gb0 + (size_t)64 * DIM;
        gemm_loop_db(ga0, ga1, 32, 32, gb0, gb1, 32, As, Bs, acc, DIM / 32);
        int rbase = mb * 128 + wm * 64 + ((lane >> 4) << 2);
        int cbase = nb * 128 + wn * 64 + (lane & 15);
#pragma unroll
        for (int j = 0; j < 4; j++) {
            int c = cbase + j * 16;
            float bias = b1[c];
#pragma unroll
            for (int i = 0; i < 4; i++)
#pragma unroll
                for (int r = 0; r < 4; r++) {
                    int row = rbase + i * 16 + r;
                    float v = acc[i][j][r] + bias;
                    float g = 0.5f * v * (1.0f + erff(v * 0.70710678118f));
                    H[(size_t)row * HID + c] = (bf16)g;
                }
        }
    } else {
        // ---- agemm1: 41 tiles x 12 N-tiles ----
        int t2 = bid - 768;
        int t = t2 % MAXTILES, nb = t2 / MAXTILES;
        int lvl = tile_meta[t];
        if (lvl < 0) return;
        int ridx0 = row_index[t * 128 + r0];
        int ridx1 = row_index[t * 128 + 64 + r0];
        const bf16* ga0 = (ridx0 >= 0) ? (Xn + (size_t)ridx0 * DIM + cg * 8) : zbuf;
        const bf16* ga1 = (ridx1 >= 0) ? (Xn + (size_t)ridx1 * DIM + cg * 8) : zbuf;
        int sa0 = (ridx0 >= 0) ? 32 : 0;
        int sa1 = (ridx1 >= 0) ? 32 : 0;
        const bf16* Bl = A1t + (size_t)lvl * HID2 * DIM;
        const bf16* gb0 = Bl + (size_t)(nb * 128 + r0) * DIM + cg * 8;
        const bf16* gb1 = gb0 + (size_t)64 * DIM;
        gemm_loop_db(ga0, ga1, sa0, sa1, gb0, gb1, 32, As, Bs, acc, DIM / 32);
        int rbase = wm * 64 + ((lane >> 4) << 2);
        int cbase = nb * 128 + wn * 64 + (lane & 15);
#pragma unroll
        for (int j = 0; j < 4; j++) {
            int c = cbase + j * 16;
            float bias = a1b[lvl * HID2 + c];
#pragma unroll
            for (int i = 0; i < 4; i++)
#pragma unroll
                for (int r = 0; r < 4; r++) {
                    int rl = rbase + i * 16 + r;
                    float v = acc[i][j][r] + bias;
                    HL[(size_t)(t * 128 + rl) * HID2 + c] = (bf16)fmaxf(v, 0.0f);
                }
        }
    }
}

// ---------------- mlp2: gemm2 split-K=2 -> bf16 partials; agemm2 -> bf16 row-space buffer ----------------
__global__ __launch_bounds__(256) void mlp2_kernel(const bf16* __restrict__ H,
                                                   const bf16* __restrict__ W2t,
                                                   bf16* __restrict__ part,   // [2][ROWS*DIM]
                                                   const bf16* __restrict__ HL,
                                                   const bf16* __restrict__ A2t,
                                                   const float* __restrict__ a2b,
                                                   const int* __restrict__ row_index,
                                                   const int* __restrict__ tile_meta,
                                                   bf16* __restrict__ apart) { // [ROWS*DIM]
    __shared__ __align__(16) bf16 As[8192], Bs[8192];
    int bid = blockIdx.x, tid = threadIdx.x;
    int r0 = tid >> 2, cg = SWZ_CG(tid);
    int lane = tid & 63, wv = tid >> 6, wm = wv >> 1, wn = wv & 1;
    f32x4 acc[4][4];
    ACC_INIT(acc);

    if (bid < 384) {
        // ---- gemm2: 32 M-tiles x 6 N-tiles x 2 K-splits, K-chunk = 1536 (48 iters) ----
        int mb = bid & 31;
        int rest = bid >> 5;        // 0..11
        int nb = rest % 6;
        int ks = rest / 6;          // 0..1
        const bf16* ga0 = H + (size_t)(mb * 128 + r0) * HID + ks * 1536 + cg * 8;
        const bf16* ga1 = ga0 + (size_t)64 * HID;
        const bf16* gb0 = W2t + (size_t)(nb * 128 + r0) * HID + ks * 1536 + cg * 8;
        const bf16* gb1 = gb0 + (size_t)64 * HID;
        gemm_loop_db(ga0, ga1, 32, 32, gb0, gb1, 32, As, Bs, acc, 48);
        bf16* pk = part + (size_t)ks * ROWS * DIM;
        int rbase = mb * 128 + wm * 64 + ((lane >> 4) << 2);
        int cbase = nb * 128 + wn * 64 + (lane & 15);
#pragma unroll
        for (int j = 0; j < 4; j++) {
            int c = cbase + j * 16;
#pragma unroll
            for (int i = 0; i < 4; i++)
#pragma unroll
                for (int r = 0; r < 4; r++) {
                    int row = rbase + i * 16 + r;
                    pk[(size_t)row * DIM + c] = (bf16)acc[i][j][r];
                }
        }
    } else {
        // ---- agemm2: 41 tiles x 6 N-tiles, K = 1536 (48 iters) ----
        int t2 = bid - 384;
        int t = t2 % MAXTILES, nb = t2 / MAXTILES;
        int lvl = tile_meta[t];
        if (lvl < 0) return;
        const bf16* ga0 = HL + (size_t)(t * 128 + r0) * HID2 + cg * 8;
        const bf16* ga1 = ga0 + (size_t)64 * HID2;
        const bf16* Bl = A2t + (size_t)lvl * DIM * HID2;
        const bf16* gb0 = Bl + (size_t)(nb * 128 + r0) * HID2 + cg * 8;
        const bf16* gb1 = gb0 + (size_t)64 * HID2;
        gemm_loop_db(ga0, ga1, 32, 32, gb0, gb1, 32, As, Bs, acc, HID2 / 32);
        int rbase = wm * 64 + ((lane >> 4) << 2);
        int cbase = nb * 128 + wn * 64 + (lane & 15);
#pragma unroll
        for (int i = 0; i < 4; i++)
#pragma unroll
            for (int r = 0; r < 4; r++) {
                int rl = rbase + i * 16 + r;
                int rg = row_index[t * 128 + rl];
                if (rg >= 0) {
#pragma unroll
                    for (int j = 0; j < 4; j++) {
                        int c = cbase + j * 16;
                        apart[(size_t)rg * DIM + c] = (bf16)(acc[i][j][r] + a2b[lvl * DIM + c]);
                    }
                }
            }
    }
}

// ---------------- combine: out = (1-mix)*(p0+p1+b2) + mix*apart ----------------
__global__ __launch_bounds__(256) void combine_kernel(const bf16* __restrict__ part,
                                                      const bf16* __restrict__ apart,
                                                      const float* __restrict__ b2,
                                                      const float* __restrict__ mix,
                                                      float* __restrict__ out) {
    int i = blockIdx.x * 256 + threadIdx.x;
    int base = i * 4;
    int row = base / DIM;
    int c = base - row * DIM;
    float mx = mix[row & (SEQ - 1)];
    bf16x4 p0 = *(const bf16x4*)(part + base);
    bf16x4 p1 = *(const bf16x4*)(part + (size_t)ROWS * DIM + base);
    bf16x4 ap = *(const bf16x4*)(apart + base);
    float4 o;
    float* po = &o.x;
#pragma unroll
    for (int k = 0; k < 4; k++) {
        float main_v = (float)p0[k] + (float)p1[k] + b2[c + k];
        po[k] = (1.0f - mx) * main_v + mx * (float)ap[k];
    }
    *(float4*)(out + base) = o;
}

// ---------------- launch ----------------
extern "C" void kernel_launch(void* const* d_in, const int* in_sizes, int n_in,
                              void* d_out, int out_size, void* d_ws, size_t ws_size,
                              hipStream_t stream) {
    const float* x    = (const float*)d_in[0];
    const int* levels = (const int*)d_in[1];
    const float* gamma= (const float*)d_in[2];
    const float* beta = (const float*)d_in[3];
    const float* W1   = (const float*)d_in[4];
    const float* b1   = (const float*)d_in[5];
    const float* W2   = (const float*)d_in[6];
    const float* b2   = (const float*)d_in[7];
    const float* A1   = (const float*)d_in[8];
    const float* a1b  = (const float*)d_in[9];
    const float* A2   = (const float*)d_in[10];
    const float* a2b  = (const float*)d_in[11];
    const float* lmw  = (const float*)d_in[12];
    float* out = (float*)d_out;

    char* p = (char*)d_ws;
    auto alloc = [&](size_t bytes) {
        char* r = p;
        p += (bytes + 255) & ~(size_t)255;
        return r;
    };
    bf16* Xn   = (bf16*)alloc((size_t)ROWS * DIM * 2);
    bf16* W1t  = (bf16*)alloc((size_t)HID * DIM * 2);
    bf16* W2t  = (bf16*)alloc((size_t)DIM * HID * 2);
    bf16* A1t  = (bf16*)alloc((size_t)NLEV * HID2 * DIM * 2);
    bf16* A2t  = (bf16*)alloc((size_t)NLEV * DIM * HID2 * 2);
    bf16* H    = (bf16*)alloc((size_t)ROWS * HID * 2);
    bf16* HL   = (bf16*)alloc((size_t)MAXPAD * HID2 * 2);
    bf16* part = (bf16*)alloc((size_t)2 * ROWS * DIM * 2);
    bf16* apart= (bf16*)alloc((size_t)ROWS * DIM * 2);
    float* mix = (float*)alloc(SEQ * 4);
    int* row_index = (int*)alloc(MAXPAD * 4);
    int* tile_meta = (int*)alloc(MAXTILES * 4);
    float* zbuf    = (float*)alloc(64);

    // prep: routing(1) + LN(4096) + W1(576) + W2(576) + A1(2592) + A2(2592)
    prep_kernel<<<dim3(1 + ROWS + 576 + 576 + 2592 + 2592), dim3(256), 0, stream>>>(
        x, levels, gamma, beta, W1, W2, A1, A2, lmw,
        Xn, W1t, W2t, A1t, A2t, mix, row_index, tile_meta, zbuf);

    // mlp1: gemm1 (768) + agemm1 (492)
    mlp1_kernel<<<dim3(768 + MAXTILES * 12), dim3(256), 0, stream>>>(
        Xn, W1t, b1, H, A1t, a1b, row_index, tile_meta, (const bf16*)zbuf, HL);

    // mlp2: gemm2 splitK2 (384) + agemm2 (246) -> partial buffers, no atomics
    mlp2_kernel<<<dim3(384 + MAXTILES * 6), dim3(256), 0, stream>>>(
        H, W2t, part, HL, A2t, a2b, row_index, tile_meta, apart);

    // combine: blend main + adapter into out
    combine_kernel<<<dim3(ROWS * DIM / 1024), dim3(256), 0, stream>>>(
        part, apart, b2, mix, out);
}